// Round 8
// baseline (660.816 us; speedup 1.0000x reference)
//
#include <hip/hip_runtime.h>
#include <math.h>

#define NN 20000
#define NE 320000
#define IN_DIM 16
#define HID 64
#define HEADS 4
#define HD 256          // HEADS*HID
#define OUTW 208        // 16 + 3*64
#define NEG 0.2f

typedef unsigned short u16;
typedef unsigned int u32;
typedef __attribute__((ext_vector_type(8))) short bf16x8;   // MFMA A/B frag
typedef __attribute__((ext_vector_type(4))) float f32x4;    // MFMA C/D frag

__device__ __forceinline__ float b2f(u16 u) {
  union { u32 i; float f; } c; c.i = ((u32)u) << 16; return c.f;
}
__device__ __forceinline__ u16 f2b(float f) {
  union { float f; u32 i; } c; c.f = f;
  u32 r = (c.i + 0x7FFFu + ((c.i >> 16) & 1u)) >> 16;
  return (u16)r;
}

// ---------------- embed: feat = node_feat @ W_embed + b; write feat, featb, out cols 0..79
__global__ void k_embed(const float* __restrict__ nf, const float* __restrict__ We,
                        const float* __restrict__ be, float* __restrict__ feat,
                        u16* __restrict__ featb, float* __restrict__ out) {
  int tid = blockIdx.x * blockDim.x + threadIdx.x;   // NN*64 threads
  int n = tid >> 6, c = tid & 63;
  if (n >= NN) return;
  float acc = be[c];
#pragma unroll
  for (int k = 0; k < IN_DIM; ++k)
    acc += nf[n * IN_DIM + k] * We[k * HID + c];
  feat[n * HID + c] = acc;
  featb[n * HID + c] = f2b(acc);
  out[n * OUTW + 16 + c] = acc;
  if (c < IN_DIM) out[n * OUTW + c] = nf[n * IN_DIM + c];
}

// ---------------- CSR build over dst
__global__ void k_count(const int* __restrict__ dst, int* __restrict__ counts) {
  int e = blockIdx.x * blockDim.x + threadIdx.x;
  if (e < NE) atomicAdd(&counts[dst[e]], 1);
}

// single block, 1024 threads, shuffle-based scan
__global__ void k_scan(const int* __restrict__ counts, int* __restrict__ rowptr) {
  __shared__ int wsum[16];
  __shared__ int tot;
  int lane = threadIdx.x & 63, wid = threadIdx.x >> 6;
  int running = 0;
  if (threadIdx.x == 0) rowptr[0] = 0;
  for (int base = 0; base < NN; base += 1024) {
    int i = base + threadIdx.x;
    int x = (i < NN) ? counts[i] : 0;
#pragma unroll
    for (int d = 1; d < 64; d <<= 1) {
      int t = __shfl_up(x, d);
      if (lane >= d) x += t;
    }
    if (lane == 63) wsum[wid] = x;
    __syncthreads();
    if (wid == 0) {
      int wv = (lane < 16) ? wsum[lane] : 0;
#pragma unroll
      for (int d = 1; d < 16; d <<= 1) {
        int t = __shfl_up(wv, d);
        if (lane >= d) wv += t;
      }
      if (lane < 16) wsum[lane] = wv;
      if (lane == 15) tot = wv;
    }
    __syncthreads();
    int wpre = (wid == 0) ? 0 : wsum[wid - 1];
    if (i < NN) rowptr[i + 1] = running + wpre + x;
    running += tot;
    __syncthreads();
  }
}

// scatter: eidx (CSR slot -> original edge), src/dst permuted into CSR order
__global__ void k_scatter(const int* __restrict__ dst, const int* __restrict__ src,
                          const int* __restrict__ rowptr, int* __restrict__ cursor,
                          int* __restrict__ eidx, int* __restrict__ srcp,
                          int* __restrict__ dstp) {
  int e = blockIdx.x * blockDim.x + threadIdx.x;
  if (e >= NE) return;
  int d = dst[e];
  int pos = rowptr[d] + atomicAdd(&cursor[d], 1);
  eidx[pos] = e;
  srcp[pos] = src[e];
  dstp[pos] = d;
}

// ---------------- coalesced f32 -> bf16 convert of edge_feat (original order)
__global__ void k_convert(const float* __restrict__ ef, u16* __restrict__ efb) {
  int t = blockIdx.x * blockDim.x + threadIdx.x;   // NE*HID/4 threads
  float4 v = *reinterpret_cast<const float4*>(&ef[(size_t)t * 4]);
  ushort4 o;
  o.x = f2b(v.x); o.y = f2b(v.y); o.z = f2b(v.z); o.w = f2b(v.w);
  *reinterpret_cast<ushort4*>(&efb[(size_t)t * 4]) = o;
}

// ---------------- transpose + bf16-convert W_fij, W_ni, W_nj -> Wt[3][n][k]
__global__ void k_prepw3(const float* __restrict__ Wf, const float* __restrict__ Wni,
                         const float* __restrict__ Wnj, u16* __restrict__ Wt) {
  int tid = blockIdx.x * blockDim.x + threadIdx.x;   // 3*HD*HID threads
  int which = tid / (HD * HID);
  int r = tid - which * (HD * HID);
  int n = r >> 6, k = r & 63;
  const float* W = (which == 0) ? Wf : ((which == 1) ? Wni : Wnj);
  Wt[which * (HD * HID) + n * HID + k] = f2b(W[k * HD + n]);
}

// ---------------- node projection: hn = feat @ W_node -> bf16 (8 nodes/block)
__global__ __launch_bounds__(256) void k_nodeproj(
    const float* __restrict__ feat, const float* __restrict__ Wnd,
    u16* __restrict__ hn) {
  __shared__ float hs[8 * HID];
  int n0 = blockIdx.x * 8;
  int c = threadIdx.x;
  for (int i = threadIdx.x; i < 8 * HID; i += 256)
    hs[i] = feat[(size_t)(n0 + (i >> 6)) * HID + (i & 63)];
  __syncthreads();
  float aN[8] = {0};
  for (int k = 0; k < HID; ++k) {
    float wn = Wnd[k * HD + c];
#pragma unroll
    for (int t = 0; t < 8; ++t)
      aN[t] += hs[t * HID + k] * wn;
  }
#pragma unroll
  for (int t = 0; t < 8; ++t)
    hn[(size_t)(n0 + t) * HD + c] = f2b(aN[t]);
}

// ---------------- edge logits: FULL MFMA (ef@Wf + feat[src]@Wni + feat[dst]@Wnj)
// block = 4 waves = 4 heads; 16 edges (CSR slots) per tile; no LDS.
// elog head-major: elog[h*NE + slot]
__global__ __launch_bounds__(256) void k_edgelogits(
    const u16* __restrict__ efb, const u16* __restrict__ featb,
    const int* __restrict__ eidx, const int* __restrict__ srcp,
    const int* __restrict__ dstp, const u16* __restrict__ Wt,
    const float* __restrict__ battL, const float* __restrict__ attnL,
    float* __restrict__ elog) {
  int h = threadIdx.x >> 6;            // wave = head
  int l = threadIdx.x & 63;
  int q = l >> 4;                      // quad
  int n = l & 15;
  // B fragments for the 3 weight matrices (this head's 64 output cols)
  const u16* WF = Wt;
  const u16* WI = Wt + HD * HID;
  const u16* WJ = Wt + 2 * HD * HID;
  bf16x8 bfF[4][2], bfI[4][2], bfJ[4][2];
#pragma unroll
  for (int nt = 0; nt < 4; ++nt) {
    int row = (h * 64 + nt * 16 + n) * HID;
#pragma unroll
    for (int kk = 0; kk < 2; ++kk) {
      bfF[nt][kk] = *reinterpret_cast<const bf16x8*>(&WF[row + kk * 32 + q * 8]);
      bfI[nt][kk] = *reinterpret_cast<const bf16x8*>(&WI[row + kk * 32 + q * 8]);
      bfJ[nt][kk] = *reinterpret_cast<const bf16x8*>(&WJ[row + kk * 32 + q * 8]);
    }
  }
  float at[4], bat[4];
#pragma unroll
  for (int nt = 0; nt < 4; ++nt) {
    at[nt] = attnL[h * 64 + nt * 16 + n];
    bat[nt] = battL[h * 64 + nt * 16 + n];
  }

  const int NT = NE / 16;  // 20000 tiles
  for (int tile = blockIdx.x; tile < NT; tile += gridDim.x) {
    int i0 = tile * 16;
    int slot = i0 + n;
    int er = eidx[slot], s = srcp[slot], d = dstp[slot];
    bf16x8 ae0 = *reinterpret_cast<const bf16x8*>(&efb[(size_t)er * HID + q * 8]);
    bf16x8 ae1 = *reinterpret_cast<const bf16x8*>(&efb[(size_t)er * HID + 32 + q * 8]);
    bf16x8 as0 = *reinterpret_cast<const bf16x8*>(&featb[(size_t)s * HID + q * 8]);
    bf16x8 as1 = *reinterpret_cast<const bf16x8*>(&featb[(size_t)s * HID + 32 + q * 8]);
    bf16x8 ad0 = *reinterpret_cast<const bf16x8*>(&featb[(size_t)d * HID + q * 8]);
    bf16x8 ad1 = *reinterpret_cast<const bf16x8*>(&featb[(size_t)d * HID + 32 + q * 8]);
    float sumr[4] = {0.f, 0.f, 0.f, 0.f};
#pragma unroll
    for (int nt = 0; nt < 4; ++nt) {
      f32x4 acc = {0.f, 0.f, 0.f, 0.f};
      acc = __builtin_amdgcn_mfma_f32_16x16x32_bf16(ae0, bfF[nt][0], acc, 0, 0, 0);
      acc = __builtin_amdgcn_mfma_f32_16x16x32_bf16(ae1, bfF[nt][1], acc, 0, 0, 0);
      acc = __builtin_amdgcn_mfma_f32_16x16x32_bf16(as0, bfI[nt][0], acc, 0, 0, 0);
      acc = __builtin_amdgcn_mfma_f32_16x16x32_bf16(as1, bfI[nt][1], acc, 0, 0, 0);
      acc = __builtin_amdgcn_mfma_f32_16x16x32_bf16(ad0, bfJ[nt][0], acc, 0, 0, 0);
      acc = __builtin_amdgcn_mfma_f32_16x16x32_bf16(ad1, bfJ[nt][1], acc, 0, 0, 0);
#pragma unroll
      for (int r = 0; r < 4; ++r) {
        float v = acc[r] + bat[nt];
        v = v > 0.f ? v : NEG * v;
        sumr[r] += v * at[nt];
      }
    }
#pragma unroll
    for (int r = 0; r < 4; ++r) {
      float v = sumr[r];
      v += __shfl_xor(v, 1);
      v += __shfl_xor(v, 2);
      v += __shfl_xor(v, 4);
      v += __shfl_xor(v, 8);
      sumr[r] = v;
    }
    if (n == 0) {
#pragma unroll
      for (int r = 0; r < 4; ++r)
        elog[(size_t)h * NE + i0 + q * 4 + r] = sumr[r];
    }
  }
}

// ---------------- per-(node,head) softmax stats (elog head-major, coalesced)
__global__ void k_mz(const int* __restrict__ rowptr, const float* __restrict__ elog,
                     float* __restrict__ mz) {
  int t = blockIdx.x * blockDim.x + threadIdx.x;
  if (t >= NN * HEADS) return;
  int h = t / NN, n = t - h * NN;
  int s0 = rowptr[n], s1 = rowptr[n + 1];
  const float* er = elog + (size_t)h * NE;
  float m = -1e30f;
  for (int i = s0; i < s1; ++i) m = fmaxf(m, er[i]);
  float z = 0.f;
  for (int i = s0; i < s1; ++i) z += __expf(er[i] - m);
  mz[n * 8 + h] = m;
  mz[n * 8 + 4 + h] = (z > 0.f) ? 1.0f / z : 0.f;
}

// ---------------- aggregation: one wave per node, unroll x8, softmax on the fly
__global__ __launch_bounds__(256) void k_agg(
    const int* __restrict__ rowptr, const int* __restrict__ srcp,
    const float* __restrict__ elog, const float* __restrict__ mz,
    const u16* __restrict__ hn, float* __restrict__ agg) {
  int n = (blockIdx.x * blockDim.x + threadIdx.x) >> 6;
  int j = threadIdx.x & 63;
  if (n >= NN) return;
  int s0 = rowptr[n], s1 = rowptr[n + 1];
  int h = j >> 4;
  float m = mz[n * 8 + h], invz = mz[n * 8 + 4 + h];
  const float* er = elog + (size_t)h * NE;
  float4 ac[8];
#pragma unroll
  for (int t = 0; t < 8; ++t) ac[t] = make_float4(0, 0, 0, 0);
  int i = s0;
  for (; i + 8 <= s1; i += 8) {
    int sv[8]; float wv[8]; ushort4 vv[8];
#pragma unroll
    for (int t = 0; t < 8; ++t) sv[t] = srcp[i + t];
#pragma unroll
    for (int t = 0; t < 8; ++t) wv[t] = __expf(er[i + t] - m) * invz;
#pragma unroll
    for (int t = 0; t < 8; ++t)
      vv[t] = *reinterpret_cast<const ushort4*>(&hn[(size_t)sv[t] * HD + 4 * j]);
#pragma unroll
    for (int t = 0; t < 8; ++t) {
      ac[t].x += b2f(vv[t].x) * wv[t]; ac[t].y += b2f(vv[t].y) * wv[t];
      ac[t].z += b2f(vv[t].z) * wv[t]; ac[t].w += b2f(vv[t].w) * wv[t];
    }
  }
  for (; i < s1; ++i) {
    int s = srcp[i];
    float w = __expf(er[i] - m) * invz;
    ushort4 v = *reinterpret_cast<const ushort4*>(&hn[(size_t)s * HD + 4 * j]);
    ac[0].x += b2f(v.x) * w; ac[0].y += b2f(v.y) * w;
    ac[0].z += b2f(v.z) * w; ac[0].w += b2f(v.w) * w;
  }
  float4 acc;
  acc.x = ((ac[0].x + ac[1].x) + (ac[2].x + ac[3].x)) + ((ac[4].x + ac[5].x) + (ac[6].x + ac[7].x));
  acc.y = ((ac[0].y + ac[1].y) + (ac[2].y + ac[3].y)) + ((ac[4].y + ac[5].y) + (ac[6].y + ac[7].y));
  acc.z = ((ac[0].z + ac[1].z) + (ac[2].z + ac[3].z)) + ((ac[4].z + ac[5].z) + (ac[6].z + ac[7].z));
  acc.w = ((ac[0].w + ac[1].w) + (ac[2].w + ac[3].w)) + ((ac[4].w + ac[5].w) + (ac[6].w + ac[7].w));
  *reinterpret_cast<float4*>(&agg[(size_t)n * HD + 4 * j]) = acc;
}

// ---------------- MLP + residual: feat = agg @ W_mlp + b + feat; write feat, featb, out
__global__ __launch_bounds__(256) void k_mlp(
    const float* __restrict__ agg, const float* __restrict__ Wm,
    const float* __restrict__ bm, float* __restrict__ feat,
    u16* __restrict__ featb, float* __restrict__ out, int outoff) {
  __shared__ float as_[32 * HD];
  int n0 = blockIdx.x * 32;
  for (int i = threadIdx.x; i < 32 * HD; i += 256) as_[i] = agg[(size_t)n0 * HD + i];
  __syncthreads();
  int c = threadIdx.x & 63;
  int g = threadIdx.x >> 6;
  float acc[8] = {0};
  for (int k = 0; k < HD; ++k) {
    float wv = Wm[k * HID + c];
#pragma unroll
    for (int t = 0; t < 8; ++t)
      acc[t] += as_[(g * 8 + t) * HD + k] * wv;
  }
  float b = bm[c];
#pragma unroll
  for (int t = 0; t < 8; ++t) {
    int n = n0 + g * 8 + t;
    float v = acc[t] + b + feat[n * HID + c];
    feat[n * HID + c] = v;
    featb[n * HID + c] = f2b(v);
    out[n * OUTW + outoff + c] = v;
  }
}

extern "C" void kernel_launch(void* const* d_in, const int* in_sizes, int n_in,
                              void* d_out, int out_size, void* d_ws, size_t ws_size,
                              hipStream_t stream) {
  const float* node_feat = (const float*)d_in[0];
  const float* edge_feat = (const float*)d_in[1];
  const int*   src       = (const int*)d_in[2];
  const int*   dst       = (const int*)d_in[3];
  const float* W_embed   = (const float*)d_in[4];
  const float* b_embed   = (const float*)d_in[5];
  const float* W_ni      = (const float*)d_in[6];
  const float* W_nj      = (const float*)d_in[7];
  const float* W_fij     = (const float*)d_in[8];
  const float* b_att     = (const float*)d_in[9];
  const float* attn      = (const float*)d_in[10];
  const float* W_node    = (const float*)d_in[11];
  const float* W_mlp     = (const float*)d_in[12];
  const float* b_mlp     = (const float*)d_in[13];
  float* out = (float*)d_out;

  // workspace layout
  float* ws    = (float*)d_ws;
  float* feat  = ws;                                   // NN*HID f32
  float* aggb  = feat + (size_t)NN * HID;              // NN*HD f32
  float* elog  = aggb + (size_t)NN * HD;               // HEADS*NE f32 (head-major)
  float* mz    = elog + (size_t)NE * HEADS;            // NN*8 f32
  u16*  featb  = (u16*)(mz + (size_t)NN * 8);          // NN*HID bf16
  u16*  hn     = featb + (size_t)NN * HID;             // NN*HD bf16
  u16*  efb    = hn + (size_t)NN * HD;                 // NE*HID bf16 (original order)
  u16*  Wt     = efb + (size_t)NE * HID;               // 3*HD*HID bf16
  int* counts  = (int*)(Wt + (size_t)3 * HD * HID);    // NN
  int* rowptr  = counts + NN;                          // NN+1
  int* cursor  = rowptr + NN + 1;                      // NN
  int* eidx    = cursor + NN;                          // NE
  int* srcp    = eidx + NE;                            // NE
  int* dstp    = srcp + NE;                            // NE

  hipMemsetAsync(counts, 0, sizeof(int) * NN, stream);
  hipMemsetAsync(cursor, 0, sizeof(int) * NN, stream);

  k_embed<<<(NN * 64) / 256, 256, 0, stream>>>(node_feat, W_embed, b_embed, feat, featb, out);
  k_count<<<NE / 256, 256, 0, stream>>>(dst, counts);
  k_scan<<<1, 1024, 0, stream>>>(counts, rowptr);
  k_scatter<<<NE / 256, 256, 0, stream>>>(dst, src, rowptr, cursor, eidx, srcp, dstp);
  k_convert<<<(NE * HID / 4) / 256, 256, 0, stream>>>(edge_feat, efb);

  for (int L = 0; L < 2; ++L) {
    const float* WniL = W_ni + (size_t)L * HID * HD;
    const float* WnjL = W_nj + (size_t)L * HID * HD;
    const float* WfL  = W_fij + (size_t)L * HID * HD;
    const float* WndL = W_node + (size_t)L * HID * HD;
    const float* battL = b_att + (size_t)L * HD;
    const float* attnL = attn + (size_t)L * HEADS * HID;
    const float* WmL  = W_mlp + (size_t)L * HD * HID;
    const float* bmL  = b_mlp + (size_t)L * HID;

    k_prepw3<<<(3 * HD * HID) / 256, 256, 0, stream>>>(WfL, WniL, WnjL, Wt);
    k_nodeproj<<<NN / 8, 256, 0, stream>>>(feat, WndL, hn);
    k_edgelogits<<<2500, 256, 0, stream>>>(efb, featb, eidx, srcp, dstp, Wt, battL, attnL, elog);
    k_mz<<<(NN * HEADS + 255) / 256, 256, 0, stream>>>(rowptr, elog, mz);
    k_agg<<<(NN * 64) / 256, 256, 0, stream>>>(rowptr, srcp, elog, mz, hn, aggb);
    k_mlp<<<NN / 32, 256, 0, stream>>>(aggb, WmL, bmL, feat, featb, out, 80 + L * 64);
  }
}

// Round 9
// 648.022 us; speedup vs baseline: 1.0197x; 1.0197x over previous
//
#include <hip/hip_runtime.h>
#include <math.h>

#define NN 20000
#define NE 320000
#define IN_DIM 16
#define HID 64
#define HEADS 4
#define HD 256          // HEADS*HID
#define OUTW 208        // 16 + 3*64
#define NEG 0.2f

typedef unsigned short u16;
typedef unsigned int u32;
typedef __attribute__((ext_vector_type(8))) short bf16x8;   // MFMA A/B frag
typedef __attribute__((ext_vector_type(4))) float f32x4;    // MFMA C/D frag

__device__ __forceinline__ float b2f(u16 u) {
  union { u32 i; float f; } c; c.i = ((u32)u) << 16; return c.f;
}
__device__ __forceinline__ u16 f2b(float f) {
  union { float f; u32 i; } c; c.f = f;
  u32 r = (c.i + 0x7FFFu + ((c.i >> 16) & 1u)) >> 16;
  return (u16)r;
}

// ---------------- embed: feat = node_feat @ W_embed + b; write feat, featb, out cols 0..79
__global__ void k_embed(const float* __restrict__ nf, const float* __restrict__ We,
                        const float* __restrict__ be, float* __restrict__ feat,
                        u16* __restrict__ featb, float* __restrict__ out) {
  int tid = blockIdx.x * blockDim.x + threadIdx.x;   // NN*64 threads
  int n = tid >> 6, c = tid & 63;
  if (n >= NN) return;
  float acc = be[c];
#pragma unroll
  for (int k = 0; k < IN_DIM; ++k)
    acc += nf[n * IN_DIM + k] * We[k * HID + c];
  feat[n * HID + c] = acc;
  featb[n * HID + c] = f2b(acc);
  out[n * OUTW + 16 + c] = acc;
  if (c < IN_DIM) out[n * OUTW + c] = nf[n * IN_DIM + c];
}

// ---------------- CSR build over dst
__global__ void k_count(const int* __restrict__ dst, int* __restrict__ counts) {
  int e = blockIdx.x * blockDim.x + threadIdx.x;
  if (e < NE) atomicAdd(&counts[dst[e]], 1);
}

// single block, 1024 threads, shuffle-based scan
__global__ void k_scan(const int* __restrict__ counts, int* __restrict__ rowptr) {
  __shared__ int wsum[16];
  __shared__ int tot;
  int lane = threadIdx.x & 63, wid = threadIdx.x >> 6;
  int running = 0;
  if (threadIdx.x == 0) rowptr[0] = 0;
  for (int base = 0; base < NN; base += 1024) {
    int i = base + threadIdx.x;
    int x = (i < NN) ? counts[i] : 0;
#pragma unroll
    for (int d = 1; d < 64; d <<= 1) {
      int t = __shfl_up(x, d);
      if (lane >= d) x += t;
    }
    if (lane == 63) wsum[wid] = x;
    __syncthreads();
    if (wid == 0) {
      int wv = (lane < 16) ? wsum[lane] : 0;
#pragma unroll
      for (int d = 1; d < 16; d <<= 1) {
        int t = __shfl_up(wv, d);
        if (lane >= d) wv += t;
      }
      if (lane < 16) wsum[lane] = wv;
      if (lane == 15) tot = wv;
    }
    __syncthreads();
    int wpre = (wid == 0) ? 0 : wsum[wid - 1];
    if (i < NN) rowptr[i + 1] = running + wpre + x;
    running += tot;
    __syncthreads();
  }
}

// scatter: eidx (CSR slot -> original edge), src/dst permuted into CSR order
__global__ void k_scatter(const int* __restrict__ dst, const int* __restrict__ src,
                          const int* __restrict__ rowptr, int* __restrict__ cursor,
                          int* __restrict__ eidx, int* __restrict__ srcp,
                          int* __restrict__ dstp) {
  int e = blockIdx.x * blockDim.x + threadIdx.x;
  if (e >= NE) return;
  int d = dst[e];
  int pos = rowptr[d] + atomicAdd(&cursor[d], 1);
  eidx[pos] = e;
  srcp[pos] = src[e];
  dstp[pos] = d;
}

// ---------------- coalesced f32 -> bf16 convert of edge_feat (original order)
__global__ void k_convert(const float* __restrict__ ef, u16* __restrict__ efb) {
  int t = blockIdx.x * blockDim.x + threadIdx.x;   // NE*HID/4 threads
  float4 v = *reinterpret_cast<const float4*>(&ef[(size_t)t * 4]);
  ushort4 o;
  o.x = f2b(v.x); o.y = f2b(v.y); o.z = f2b(v.z); o.w = f2b(v.w);
  *reinterpret_cast<ushort4*>(&efb[(size_t)t * 4]) = o;
}

// ---------------- transpose + bf16-convert W_fij, W_ni, W_nj -> Wt[3][n][k]
__global__ void k_prepw3(const float* __restrict__ Wf, const float* __restrict__ Wni,
                         const float* __restrict__ Wnj, u16* __restrict__ Wt) {
  int tid = blockIdx.x * blockDim.x + threadIdx.x;   // 3*HD*HID threads
  int which = tid / (HD * HID);
  int r = tid - which * (HD * HID);
  int n = r >> 6, k = r & 63;
  const float* W = (which == 0) ? Wf : ((which == 1) ? Wni : Wnj);
  Wt[which * (HD * HID) + n * HID + k] = f2b(W[k * HD + n]);
}

// ---------------- node projection: hn = feat @ W_node -> bf16 (8 nodes/block)
__global__ __launch_bounds__(256) void k_nodeproj(
    const float* __restrict__ feat, const float* __restrict__ Wnd,
    u16* __restrict__ hn) {
  __shared__ float hs[8 * HID];
  int n0 = blockIdx.x * 8;
  int c = threadIdx.x;
  for (int i = threadIdx.x; i < 8 * HID; i += 256)
    hs[i] = feat[(size_t)(n0 + (i >> 6)) * HID + (i & 63)];
  __syncthreads();
  float aN[8] = {0};
  for (int k = 0; k < HID; ++k) {
    float wn = Wnd[k * HD + c];
#pragma unroll
    for (int t = 0; t < 8; ++t)
      aN[t] += hs[t * HID + k] * wn;
  }
#pragma unroll
  for (int t = 0; t < 8; ++t)
    hn[(size_t)(n0 + t) * HD + c] = f2b(aN[t]);
}

// ---------------- edge logits: FULL MFMA (ef@Wf + feat[src]@Wni + feat[dst]@Wnj)
// block = 4 waves = 4 heads; 16 edges (CSR slots) per tile; no LDS.
// launch_bounds(256,3): ~170 VGPR cap so the 96 VGPRs of B-fragments stay resident.
// elog head-major: elog[h*NE + slot]
__global__ __launch_bounds__(256, 3) void k_edgelogits(
    const u16* __restrict__ efb, const u16* __restrict__ featb,
    const int* __restrict__ eidx, const int* __restrict__ srcp,
    const int* __restrict__ dstp, const u16* __restrict__ Wt,
    const float* __restrict__ battL, const float* __restrict__ attnL,
    float* __restrict__ elog) {
  int h = threadIdx.x >> 6;            // wave = head
  int l = threadIdx.x & 63;
  int q = l >> 4;                      // quad
  int n = l & 15;
  // B fragments for the 3 weight matrices (this head's 64 output cols)
  const u16* WF = Wt;
  const u16* WI = Wt + HD * HID;
  const u16* WJ = Wt + 2 * HD * HID;
  bf16x8 bfF[4][2], bfI[4][2], bfJ[4][2];
#pragma unroll
  for (int nt = 0; nt < 4; ++nt) {
    int row = (h * 64 + nt * 16 + n) * HID;
#pragma unroll
    for (int kk = 0; kk < 2; ++kk) {
      bfF[nt][kk] = *reinterpret_cast<const bf16x8*>(&WF[row + kk * 32 + q * 8]);
      bfI[nt][kk] = *reinterpret_cast<const bf16x8*>(&WI[row + kk * 32 + q * 8]);
      bfJ[nt][kk] = *reinterpret_cast<const bf16x8*>(&WJ[row + kk * 32 + q * 8]);
    }
  }
  float at[4], bat[4];
#pragma unroll
  for (int nt = 0; nt < 4; ++nt) {
    at[nt] = attnL[h * 64 + nt * 16 + n];
    bat[nt] = battL[h * 64 + nt * 16 + n];
  }

  const int NT = NE / 16;  // 20000 tiles
  for (int tile = blockIdx.x; tile < NT; tile += gridDim.x) {
    int i0 = tile * 16;
    int slot = i0 + n;
    int er = eidx[slot], s = srcp[slot], d = dstp[slot];
    bf16x8 ae0 = *reinterpret_cast<const bf16x8*>(&efb[(size_t)er * HID + q * 8]);
    bf16x8 ae1 = *reinterpret_cast<const bf16x8*>(&efb[(size_t)er * HID + 32 + q * 8]);
    bf16x8 as0 = *reinterpret_cast<const bf16x8*>(&featb[(size_t)s * HID + q * 8]);
    bf16x8 as1 = *reinterpret_cast<const bf16x8*>(&featb[(size_t)s * HID + 32 + q * 8]);
    bf16x8 ad0 = *reinterpret_cast<const bf16x8*>(&featb[(size_t)d * HID + q * 8]);
    bf16x8 ad1 = *reinterpret_cast<const bf16x8*>(&featb[(size_t)d * HID + 32 + q * 8]);
    float sumr[4] = {0.f, 0.f, 0.f, 0.f};
#pragma unroll
    for (int nt = 0; nt < 4; ++nt) {
      // two independent 3-deep MFMA chains (k-halves) for ILP
      f32x4 accA = {0.f, 0.f, 0.f, 0.f};
      f32x4 accB = {0.f, 0.f, 0.f, 0.f};
      accA = __builtin_amdgcn_mfma_f32_16x16x32_bf16(ae0, bfF[nt][0], accA, 0, 0, 0);
      accB = __builtin_amdgcn_mfma_f32_16x16x32_bf16(ae1, bfF[nt][1], accB, 0, 0, 0);
      accA = __builtin_amdgcn_mfma_f32_16x16x32_bf16(as0, bfI[nt][0], accA, 0, 0, 0);
      accB = __builtin_amdgcn_mfma_f32_16x16x32_bf16(as1, bfI[nt][1], accB, 0, 0, 0);
      accA = __builtin_amdgcn_mfma_f32_16x16x32_bf16(ad0, bfJ[nt][0], accA, 0, 0, 0);
      accB = __builtin_amdgcn_mfma_f32_16x16x32_bf16(ad1, bfJ[nt][1], accB, 0, 0, 0);
#pragma unroll
      for (int r = 0; r < 4; ++r) {
        float v = accA[r] + accB[r] + bat[nt];
        v = v > 0.f ? v : NEG * v;
        sumr[r] += v * at[nt];
      }
    }
#pragma unroll
    for (int r = 0; r < 4; ++r) {
      float v = sumr[r];
      v += __shfl_xor(v, 1);
      v += __shfl_xor(v, 2);
      v += __shfl_xor(v, 4);
      v += __shfl_xor(v, 8);
      sumr[r] = v;
    }
    if (n == 0) {
#pragma unroll
      for (int r = 0; r < 4; ++r)
        elog[(size_t)h * NE + i0 + q * 4 + r] = sumr[r];
    }
  }
}

// ---------------- per-(node,head) softmax stats (elog head-major, coalesced)
__global__ void k_mz(const int* __restrict__ rowptr, const float* __restrict__ elog,
                     float* __restrict__ mz) {
  int t = blockIdx.x * blockDim.x + threadIdx.x;
  if (t >= NN * HEADS) return;
  int h = t / NN, n = t - h * NN;
  int s0 = rowptr[n], s1 = rowptr[n + 1];
  const float* er = elog + (size_t)h * NE;
  float m = -1e30f;
  for (int i = s0; i < s1; ++i) m = fmaxf(m, er[i]);
  float z = 0.f;
  for (int i = s0; i < s1; ++i) z += __expf(er[i] - m);
  mz[n * 8 + h] = m;
  mz[n * 8 + 4 + h] = (z > 0.f) ? 1.0f / z : 0.f;
}

// ---------------- aggregation: one wave per node, unroll x8, softmax on the fly
__global__ __launch_bounds__(256) void k_agg(
    const int* __restrict__ rowptr, const int* __restrict__ srcp,
    const float* __restrict__ elog, const float* __restrict__ mz,
    const u16* __restrict__ hn, float* __restrict__ agg) {
  int n = (blockIdx.x * blockDim.x + threadIdx.x) >> 6;
  int j = threadIdx.x & 63;
  if (n >= NN) return;
  int s0 = rowptr[n], s1 = rowptr[n + 1];
  int h = j >> 4;
  float m = mz[n * 8 + h], invz = mz[n * 8 + 4 + h];
  const float* er = elog + (size_t)h * NE;
  float4 ac[8];
#pragma unroll
  for (int t = 0; t < 8; ++t) ac[t] = make_float4(0, 0, 0, 0);
  int i = s0;
  for (; i + 8 <= s1; i += 8) {
    int sv[8]; float wv[8]; ushort4 vv[8];
#pragma unroll
    for (int t = 0; t < 8; ++t) sv[t] = srcp[i + t];
#pragma unroll
    for (int t = 0; t < 8; ++t) wv[t] = __expf(er[i + t] - m) * invz;
#pragma unroll
    for (int t = 0; t < 8; ++t)
      vv[t] = *reinterpret_cast<const ushort4*>(&hn[(size_t)sv[t] * HD + 4 * j]);
#pragma unroll
    for (int t = 0; t < 8; ++t) {
      ac[t].x += b2f(vv[t].x) * wv[t]; ac[t].y += b2f(vv[t].y) * wv[t];
      ac[t].z += b2f(vv[t].z) * wv[t]; ac[t].w += b2f(vv[t].w) * wv[t];
    }
  }
  for (; i < s1; ++i) {
    int s = srcp[i];
    float w = __expf(er[i] - m) * invz;
    ushort4 v = *reinterpret_cast<const ushort4*>(&hn[(size_t)s * HD + 4 * j]);
    ac[0].x += b2f(v.x) * w; ac[0].y += b2f(v.y) * w;
    ac[0].z += b2f(v.z) * w; ac[0].w += b2f(v.w) * w;
  }
  float4 acc;
  acc.x = ((ac[0].x + ac[1].x) + (ac[2].x + ac[3].x)) + ((ac[4].x + ac[5].x) + (ac[6].x + ac[7].x));
  acc.y = ((ac[0].y + ac[1].y) + (ac[2].y + ac[3].y)) + ((ac[4].y + ac[5].y) + (ac[6].y + ac[7].y));
  acc.z = ((ac[0].z + ac[1].z) + (ac[2].z + ac[3].z)) + ((ac[4].z + ac[5].z) + (ac[6].z + ac[7].z));
  acc.w = ((ac[0].w + ac[1].w) + (ac[2].w + ac[3].w)) + ((ac[4].w + ac[5].w) + (ac[6].w + ac[7].w));
  *reinterpret_cast<float4*>(&agg[(size_t)n * HD + 4 * j]) = acc;
}

// ---------------- MLP + residual: feat = agg @ W_mlp + b + feat; write feat, featb, out
__global__ __launch_bounds__(256) void k_mlp(
    const float* __restrict__ agg, const float* __restrict__ Wm,
    const float* __restrict__ bm, float* __restrict__ feat,
    u16* __restrict__ featb, float* __restrict__ out, int outoff) {
  __shared__ float as_[32 * HD];
  int n0 = blockIdx.x * 32;
  for (int i = threadIdx.x; i < 32 * HD; i += 256) as_[i] = agg[(size_t)n0 * HD + i];
  __syncthreads();
  int c = threadIdx.x & 63;
  int g = threadIdx.x >> 6;
  float acc[8] = {0};
  for (int k = 0; k < HD; ++k) {
    float wv = Wm[k * HID + c];
#pragma unroll
    for (int t = 0; t < 8; ++t)
      acc[t] += as_[(g * 8 + t) * HD + k] * wv;
  }
  float b = bm[c];
#pragma unroll
  for (int t = 0; t < 8; ++t) {
    int n = n0 + g * 8 + t;
    float v = acc[t] + b + feat[n * HID + c];
    feat[n * HID + c] = v;
    featb[n * HID + c] = f2b(v);
    out[n * OUTW + outoff + c] = v;
  }
}

extern "C" void kernel_launch(void* const* d_in, const int* in_sizes, int n_in,
                              void* d_out, int out_size, void* d_ws, size_t ws_size,
                              hipStream_t stream) {
  const float* node_feat = (const float*)d_in[0];
  const float* edge_feat = (const float*)d_in[1];
  const int*   src       = (const int*)d_in[2];
  const int*   dst       = (const int*)d_in[3];
  const float* W_embed   = (const float*)d_in[4];
  const float* b_embed   = (const float*)d_in[5];
  const float* W_ni      = (const float*)d_in[6];
  const float* W_nj      = (const float*)d_in[7];
  const float* W_fij     = (const float*)d_in[8];
  const float* b_att     = (const float*)d_in[9];
  const float* attn      = (const float*)d_in[10];
  const float* W_node    = (const float*)d_in[11];
  const float* W_mlp     = (const float*)d_in[12];
  const float* b_mlp     = (const float*)d_in[13];
  float* out = (float*)d_out;

  // workspace layout
  float* ws    = (float*)d_ws;
  float* feat  = ws;                                   // NN*HID f32
  float* aggb  = feat + (size_t)NN * HID;              // NN*HD f32
  float* elog  = aggb + (size_t)NN * HD;               // HEADS*NE f32 (head-major)
  float* mz    = elog + (size_t)NE * HEADS;            // NN*8 f32
  u16*  featb  = (u16*)(mz + (size_t)NN * 8);          // NN*HID bf16
  u16*  hn     = featb + (size_t)NN * HID;             // NN*HD bf16
  u16*  efb    = hn + (size_t)NN * HD;                 // NE*HID bf16 (original order)
  u16*  Wt     = efb + (size_t)NE * HID;               // 3*HD*HID bf16
  int* counts  = (int*)(Wt + (size_t)3 * HD * HID);    // NN
  int* rowptr  = counts + NN;                          // NN+1
  int* cursor  = rowptr + NN + 1;                      // NN
  int* eidx    = cursor + NN;                          // NE
  int* srcp    = eidx + NE;                            // NE
  int* dstp    = srcp + NE;                            // NE

  hipMemsetAsync(counts, 0, sizeof(int) * NN, stream);
  hipMemsetAsync(cursor, 0, sizeof(int) * NN, stream);

  k_embed<<<(NN * 64) / 256, 256, 0, stream>>>(node_feat, W_embed, b_embed, feat, featb, out);
  k_count<<<NE / 256, 256, 0, stream>>>(dst, counts);
  k_scan<<<1, 1024, 0, stream>>>(counts, rowptr);
  k_scatter<<<NE / 256, 256, 0, stream>>>(dst, src, rowptr, cursor, eidx, srcp, dstp);
  k_convert<<<(NE * HID / 4) / 256, 256, 0, stream>>>(edge_feat, efb);

  for (int L = 0; L < 2; ++L) {
    const float* WniL = W_ni + (size_t)L * HID * HD;
    const float* WnjL = W_nj + (size_t)L * HID * HD;
    const float* WfL  = W_fij + (size_t)L * HID * HD;
    const float* WndL = W_node + (size_t)L * HID * HD;
    const float* battL = b_att + (size_t)L * HD;
    const float* attnL = attn + (size_t)L * HEADS * HID;
    const float* WmL  = W_mlp + (size_t)L * HD * HID;
    const float* bmL  = b_mlp + (size_t)L * HID;

    k_prepw3<<<(3 * HD * HID) / 256, 256, 0, stream>>>(WfL, WniL, WnjL, Wt);
    k_nodeproj<<<NN / 8, 256, 0, stream>>>(feat, WndL, hn);
    k_edgelogits<<<4000, 256, 0, stream>>>(efb, featb, eidx, srcp, dstp, Wt, battL, attnL, elog);
    k_mz<<<(NN * HEADS + 255) / 256, 256, 0, stream>>>(rowptr, elog, mz);
    k_agg<<<(NN * 64) / 256, 256, 0, stream>>>(rowptr, srcp, elog, mz, hn, aggb);
    k_mlp<<<NN / 32, 256, 0, stream>>>(aggb, WmL, bmL, feat, featb, out, 80 + L * 64);
  }
}